// Round 1
// baseline (852.255 us; speedup 1.0000x reference)
//
#include <hip/hip_runtime.h>
#include <hip/hip_bf16.h>

#define IGNORE_INDEX (-100)

typedef __bf16 bf16_t;
typedef __bf16 bf16x8 __attribute__((ext_vector_type(8)));
typedef float f32x4 __attribute__((ext_vector_type(4)));

constexpr int NTOK = 4096;
constexpr int HID  = 2048;
constexpr int VOC  = 32000;
constexpr int BM = 128, BN = 128, BK = 32;
constexpr int NT_N = VOC / BN;  // 250 n-tiles
constexpr int NT_M = NTOK / BM; // 32 m-tiles

// ---- ws layout (bytes) ----
// Wbf  @ 0          : 32000*2048*2 = 131,072,000
// Xbf  @ 131072000  :  4096*2048*2 =  16,777,216
// pmax @ 147849216  :   250*4096*4 =   4,096,000   ([ntile][row])
// psum @ 151945216  :   250*4096*4 =   4,096,000
// xt   @ 156041216  :      4096*4  =      16,384
// loss @ 156057600  :      4096*4  =      16,384
// total ~148.9 MB

__device__ __forceinline__ unsigned short f2bf(float f) {
  unsigned int x = __float_as_uint(f);
  return (unsigned short)((x + 0x7fffu + ((x >> 16) & 1u)) >> 16);  // RNE
}

__global__ void cvt_kernel(const float* __restrict__ src, unsigned short* __restrict__ dst, size_t n4) {
  size_t i = (size_t)blockIdx.x * blockDim.x + threadIdx.x;
  size_t stride = (size_t)gridDim.x * blockDim.x;
  const float4* s4 = reinterpret_cast<const float4*>(src);
  ushort4* d4 = reinterpret_cast<ushort4*>(dst);
  for (; i < n4; i += stride) {
    float4 a = s4[i];
    ushort4 o;
    o.x = f2bf(a.x); o.y = f2bf(a.y); o.z = f2bf(a.z); o.w = f2bf(a.w);
    d4[i] = o;
  }
}

// x_t[row] = dot(X[row], W[target[row]]) + bias[target[row]]   (fp32, exact-ish)
__global__ void xt_kernel(const float* __restrict__ X, const float* __restrict__ W,
                          const float* __restrict__ bias, const int* __restrict__ tgt,
                          float* __restrict__ xt) {
  int row = blockIdx.x * 4 + (threadIdx.x >> 6);
  int lane = threadIdx.x & 63;
  if (row >= NTOK) return;
  int t = tgt[row];
  if (t < 0 || t >= VOC) { if (lane == 0) xt[row] = 0.0f; return; }
  const float4* xr = reinterpret_cast<const float4*>(X + (size_t)row * HID);
  const float4* wr = reinterpret_cast<const float4*>(W + (size_t)t * HID);
  float s = 0.0f;
  for (int i = lane; i < HID / 4; i += 64) {
    float4 a = xr[i], b = wr[i];
    s += a.x * b.x + a.y * b.y + a.z * b.z + a.w * b.w;
  }
#pragma unroll
  for (int d = 1; d < 64; d <<= 1) s += __shfl_xor(s, d);
  if (lane == 0) xt[row] = s + bias[t];
}

// Fused bf16 GEMM (logits tile) + per-row (max, sumexp) partials.
// m97 structure: 128x128 tile, BK=32, 4 waves 2x2, global_load_lds width 16.
__global__ __launch_bounds__(256) void gemm_lse_kernel(
    const bf16_t* __restrict__ Xb, const bf16_t* __restrict__ Wb,
    const float* __restrict__ bias,
    float* __restrict__ pmax, float* __restrict__ psum) {
  __shared__ bf16_t As[BM * BK];   // [128][32] row-major
  __shared__ bf16_t Bs[BN * BK];   // [128][32] row-major (W rows, K contiguous)
  __shared__ float redM[2][BM];
  __shared__ float redS[2][BM];

  const int bid = blockIdx.x;
  const int mtile = bid / NT_N;
  const int ntile = bid % NT_N;
  const int mbase = mtile * BM;
  const int nbase = ntile * BN;
  const int t = threadIdx.x;
  const int w = t >> 6;
  const int lane = t & 63;
  const int wr = w >> 1, wc = w & 1;   // wave -> 64x64 sub-tile
  const int l15 = lane & 15;
  const int kgrp = lane >> 4;          // 0..3

  // staging: lane l of wave w covers LDS element (w*512 + l*8) [+2048 for r=1]
  // -> row = 64*r + w*16 + (l>>2), kk = (l&3)*8  (matches linear wave-uniform-base+lane*16 DMA)
  const int srow = w * 16 + (lane >> 2);
  const int skk = (lane & 3) * 8;
  const bf16_t* aSrc0 = Xb + (size_t)(mbase + srow) * HID + skk;
  const bf16_t* aSrc1 = aSrc0 + (size_t)64 * HID;
  const bf16_t* bSrc0 = Wb + (size_t)(nbase + srow) * HID + skk;
  const bf16_t* bSrc1 = bSrc0 + (size_t)64 * HID;

  f32x4 acc[4][4];
#pragma unroll
  for (int mi = 0; mi < 4; ++mi)
#pragma unroll
    for (int ni = 0; ni < 4; ++ni)
#pragma unroll
      for (int j = 0; j < 4; ++j) acc[mi][ni][j] = 0.0f;

  for (int k0 = 0; k0 < HID; k0 += BK) {
    __syncthreads();
    __builtin_amdgcn_global_load_lds((const __attribute__((address_space(1))) void*)(aSrc0 + k0),
                                     (__attribute__((address_space(3))) void*)(As + w * 512), 16, 0, 0);
    __builtin_amdgcn_global_load_lds((const __attribute__((address_space(1))) void*)(aSrc1 + k0),
                                     (__attribute__((address_space(3))) void*)(As + 2048 + w * 512), 16, 0, 0);
    __builtin_amdgcn_global_load_lds((const __attribute__((address_space(1))) void*)(bSrc0 + k0),
                                     (__attribute__((address_space(3))) void*)(Bs + w * 512), 16, 0, 0);
    __builtin_amdgcn_global_load_lds((const __attribute__((address_space(1))) void*)(bSrc1 + k0),
                                     (__attribute__((address_space(3))) void*)(Bs + 2048 + w * 512), 16, 0, 0);
    __syncthreads();

    bf16x8 af[4], bfr[4];
#pragma unroll
    for (int mi = 0; mi < 4; ++mi)
      af[mi] = *reinterpret_cast<const bf16x8*>(As + (wr * 64 + mi * 16 + l15) * BK + kgrp * 8);
#pragma unroll
    for (int ni = 0; ni < 4; ++ni)
      bfr[ni] = *reinterpret_cast<const bf16x8*>(Bs + (wc * 64 + ni * 16 + l15) * BK + kgrp * 8);
#pragma unroll
    for (int mi = 0; mi < 4; ++mi)
#pragma unroll
      for (int ni = 0; ni < 4; ++ni)
        acc[mi][ni] = __builtin_amdgcn_mfma_f32_16x16x32_bf16(af[mi], bfr[ni], acc[mi][ni], 0, 0, 0);
  }

  // epilogue: C frag layout col = lane&15, row = (lane>>4)*4 + j  (m89-verified)
  float bv[4];
#pragma unroll
  for (int ni = 0; ni < 4; ++ni) bv[ni] = bias[nbase + wc * 64 + ni * 16 + l15];

#pragma unroll
  for (int mi = 0; mi < 4; ++mi) {
#pragma unroll
    for (int j = 0; j < 4; ++j) {
      float v0 = acc[mi][0][j] + bv[0];
      float v1 = acc[mi][1][j] + bv[1];
      float v2 = acc[mi][2][j] + bv[2];
      float v3 = acc[mi][3][j] + bv[3];
      float mx = fmaxf(fmaxf(v0, v1), fmaxf(v2, v3));
#pragma unroll
      for (int d = 1; d < 16; d <<= 1) mx = fmaxf(mx, __shfl_xor(mx, d));
      float s = __expf(v0 - mx) + __expf(v1 - mx) + __expf(v2 - mx) + __expf(v3 - mx);
#pragma unroll
      for (int d = 1; d < 16; d <<= 1) s += __shfl_xor(s, d);
      if (l15 == 0) {
        int lr = wr * 64 + mi * 16 + kgrp * 4 + j;
        redM[wc][lr] = mx;
        redS[wc][lr] = s;
      }
    }
  }
  __syncthreads();
  if (t < BM) {
    float m0 = redM[0][t], m1 = redM[1][t];
    float M = fmaxf(m0, m1);
    float S = __expf(m0 - M) * redS[0][t] + __expf(m1 - M) * redS[1][t];
    size_t row = (size_t)mbase + t;
    pmax[(size_t)ntile * NTOK + row] = M;   // coalesced over t
    psum[(size_t)ntile * NTOK + row] = S;
  }
}

// merge 250 partials per row -> lse -> per-row loss
__global__ void lse_kernel(const float* __restrict__ pmax, const float* __restrict__ psum,
                           const float* __restrict__ xt, const int* __restrict__ tgt,
                           float* __restrict__ loss) {
  int row = blockIdx.x * 4 + (threadIdx.x >> 6);
  int lane = threadIdx.x & 63;
  if (row >= NTOK) return;
  float M = -3.4e38f;
  for (int i = lane; i < NT_N; i += 64) M = fmaxf(M, pmax[(size_t)i * NTOK + row]);
#pragma unroll
  for (int d = 1; d < 64; d <<= 1) M = fmaxf(M, __shfl_xor(M, d));
  float S = 0.0f;
  for (int i = lane; i < NT_N; i += 64)
    S += __expf(pmax[(size_t)i * NTOK + row] - M) * psum[(size_t)i * NTOK + row];
#pragma unroll
  for (int d = 1; d < 64; d <<= 1) S += __shfl_xor(S, d);
  if (lane == 0) {
    int tg = tgt[row];
    bool valid = (tg != IGNORE_INDEX);
    float lse = M + __logf(S);
    loss[row] = valid ? (lse - xt[row]) : 0.0f;
  }
}

__global__ void final_kernel(const float* __restrict__ loss, const int* __restrict__ tgt,
                             float* __restrict__ out) {
  __shared__ float shs[256];
  __shared__ float shc[256];
  int tid = threadIdx.x;
  float s = 0.0f, c = 0.0f;
  for (int i = tid; i < NTOK; i += 256) {
    s += loss[i];
    c += (tgt[i] != IGNORE_INDEX) ? 1.0f : 0.0f;
  }
  shs[tid] = s; shc[tid] = c;
  __syncthreads();
  for (int off = 128; off > 0; off >>= 1) {
    if (tid < off) { shs[tid] += shs[tid + off]; shc[tid] += shc[tid + off]; }
    __syncthreads();
  }
  if (tid == 0) out[0] = shs[0] / fmaxf(shc[0], 1.0f);
}

extern "C" void kernel_launch(void* const* d_in, const int* in_sizes, int n_in,
                              void* d_out, int out_size, void* d_ws, size_t ws_size,
                              hipStream_t stream) {
  const float* W    = (const float*)d_in[0];  // [32000][2048]
  const float* X    = (const float*)d_in[1];  // [4096][2048]
  const int*   tgt  = (const int*)d_in[2];    // [4096]
  const float* bias = (const float*)d_in[3];  // [32000]
  float* out = (float*)d_out;

  char* ws = (char*)d_ws;
  bf16_t* Wb   = (bf16_t*)(ws);
  bf16_t* Xb   = (bf16_t*)(ws + 131072000);
  float*  pmax = (float*) (ws + 147849216);
  float*  psum = (float*) (ws + 151945216);
  float*  xt   = (float*) (ws + 156041216);
  float*  loss = (float*) (ws + 156057600);

  cvt_kernel<<<2048, 256, 0, stream>>>(W, (unsigned short*)Wb, (size_t)VOC * HID / 4);
  cvt_kernel<<<512, 256, 0, stream>>>(X, (unsigned short*)Xb, (size_t)NTOK * HID / 4);
  xt_kernel<<<NTOK / 4, 256, 0, stream>>>(X, W, bias, tgt, xt);
  gemm_lse_kernel<<<NT_M * NT_N, 256, 0, stream>>>(Xb, Wb, bias, pmax, psum);
  lse_kernel<<<NTOK / 4, 256, 0, stream>>>(pmax, psum, xt, tgt, loss);
  final_kernel<<<1, 256, 0, stream>>>(loss, tgt, out);
}